// Round 1
// baseline (269.619 us; speedup 1.0000x reference)
//
#include <hip/hip_runtime.h>

// Problem: B=1, L=2048, DIM=16, HEADS=1, DIM_HEAD=1.
// softmax over the size-1 heads axis == 1.0 -> attention is all-ones, q,k dead.
// out[0,i,j,d] = v_i * W_out[d,0] + b_out[d] for ALL j, with
// v_i = x[i,:] . W_qkv[2,:].
// => the kernel is a 2048x16 row table broadcast into a 256 MiB output.
//
// This version vs previous (261 µs):
//  - single fused kernel (no compute_rows dispatch, no workspace round-trip);
//    each block recomputes its row's 16-FMA dot redundantly (64 B, L1-broadcast)
//  - NONTEMPORAL stores: 256 MiB of streaming writes must not allocate in the
//    32 MiB aggregate L2. The harness's own fillBuffer sustains 6.56 TB/s of
//    writes; regular stores in fill_rows reached only ~2.8 TB/s.

#define L_SEQ 2048
#define DIM 16

typedef float f4 __attribute__((ext_vector_type(4)));

__global__ void __launch_bounds__(256) fused_attention_fill(
    const float* __restrict__ x,
    const float* __restrict__ W_qkv,
    const float* __restrict__ W_out,
    const float* __restrict__ b_out,
    f4* __restrict__ out) {
    const int i = blockIdx.x;   // row index, 0..2047
    const int t = threadIdx.x;  // 0..255

    // v_i = x[i,:] . W_qkv[2,:] — all 256 threads load the same 64+64 bytes
    // (L1 broadcast), 4 packed FMAs each. Cheaper than a ws round-trip.
    const f4* xi = (const f4*)(x + i * DIM);
    const f4* wv = (const f4*)(W_qkv + 2 * DIM);  // v-projection row
    f4 acc = xi[0] * wv[0] + xi[1] * wv[1] + xi[2] * wv[2] + xi[3] * wv[3];
    const float v = acc.x + acc.y + acc.z + acc.w;

    // Thread t owns d-group (t & 3): one float4 of the 16-float row pattern.
    const int dg = t & 3;
    const f4 wo = ((const f4*)W_out)[dg];
    const f4 bo = ((const f4*)b_out)[dg];
    const f4 val = v * wo + bo;

    // Row i spans L*DIM = 32768 floats = 8192 float4 = 128 KiB.
    // Thread t writes f4 slots t, t+256, ... (256%4==0 keeps dg invariant).
    // Per wave-instruction: 64 lanes x 16 B = 1 KiB contiguous, coalesced.
    f4* row_out = out + (size_t)i * (L_SEQ * DIM / 4);
#pragma unroll
    for (int k = 0; k < (L_SEQ * DIM / 4) / 256; ++k) {  // 32 stores
        __builtin_nontemporal_store(val, &row_out[t + k * 256]);
    }
}

extern "C" void kernel_launch(void* const* d_in, const int* in_sizes, int n_in,
                              void* d_out, int out_size, void* d_ws, size_t ws_size,
                              hipStream_t stream) {
    const float* x     = (const float*)d_in[0];  // (1, 2048, 16)
    const float* W_qkv = (const float*)d_in[1];  // (3, 16)
    const float* W_out = (const float*)d_in[2];  // (16, 1)
    const float* b_out = (const float*)d_in[3];  // (16,)

    fused_attention_fill<<<L_SEQ, 256, 0, stream>>>(x, W_qkv, W_out, b_out,
                                                    (f4*)d_out);
}